// Round 1
// baseline (3165.080 us; speedup 1.0000x reference)
//
#include <hip/hip_runtime.h>
#include <math.h>

#define N_PATCHES 131072
#define LSEQ 8
#define DL 64
#define NH 2
#define DKH 32
#define HALFD 16
#define DFF 128
#define DM 128

// LDS strides (dwords), chosen so hot b32 access patterns are <=2 lanes/bank:
// s_xn: addr = pg*521 + t*65 + k  -> bank = (9*pg + t + k) % 32  (<=2/bank)
// s_kv: addr = pg*1061 + t*132 + c -> bank = (5*pg + 4*t + c) % 32 (<=2/bank);
//        attention reads vary pg only -> 8 distinct banks, broadcast within t-group.
#define XN_ST 65
#define XN_SP 521
#define KV_ST 132
#define KV_SP 1061

__global__ __launch_bounds__(64, 1)
void enc_kernel(const int* __restrict__ tokens,
                const int* __restrict__ lengths,
                const float* __restrict__ emb,
                const float* __restrict__ qkvw,
                const float* __restrict__ wo,
                const float* __restrict__ n1w,
                const float* __restrict__ n2w,
                const float* __restrict__ w1,
                const float* __restrict__ w2,
                const float* __restrict__ nw,
                const float* __restrict__ pw,
                const float* __restrict__ pb,
                float* __restrict__ out)
{
    __shared__ float s_xn[8 * XN_SP];   // 16.7 KB: xn / q / p / attn-out / x2n / pooled staging (own-row only)
    __shared__ float s_kv[8 * KV_SP];   // 34.0 KB: k(0..64)|v(64..128), later hact(0..128)

    const int lane = threadIdx.x & 63;
    const int t    = lane & 7;          // token
    const int pg   = lane >> 3;         // patch-in-wave
    const int patch = blockIdx.x * 8 + pg;

    const int xnb = pg * XN_SP + t * XN_ST;
    const int kvb = pg * KV_SP + t * KV_ST;

    // ---------------- embedding gather: x[64] in regs ----------------
    const int tok = tokens[patch * LSEQ + t];
    float x[DL];
    {
        const float4* er = reinterpret_cast<const float4*>(emb) + tok * (DL / 4);
        #pragma unroll
        for (int i = 0; i < DL / 4; ++i) {
            const float4 f = er[i];
            x[4*i+0] = f.x; x[4*i+1] = f.y; x[4*i+2] = f.z; x[4*i+3] = f.w;
        }
    }

    // ---------------- rmsnorm1 -> s_xn (own row) ----------------
    {
        float ss = 0.f;
        #pragma unroll
        for (int k = 0; k < DL; ++k) ss = fmaf(x[k], x[k], ss);
        const float rstd = 1.0f / sqrtf(ss * (1.0f / 64.0f) + 1.1920928955078125e-07f);
        #pragma unroll
        for (int k = 0; k < DL; ++k) s_xn[xnb + k] = x[k] * n1w[k] * rstd;
    }

    // rope tables for this lane's token position t
    float cs[HALFD], sn[HALFD];
    #pragma unroll
    for (int i = 0; i < HALFD; ++i) {
        // freq_i = (1e-4)^(i/15) = 2^(i * log2(1e-4)/15)
        const float fr = exp2f((float)i * (-13.287712379549449f / 15.0f));
        const float th = (float)t * fr;
        cs[i] = cosf(th);
        sn[i] = sinf(th);
    }

    float acc[DL];
    float q[DL];

    // ---------------- qkv pass 0: q ----------------
    #pragma unroll
    for (int j = 0; j < DL; ++j) acc[j] = 0.f;
    #pragma unroll 2
    for (int k = 0; k < DL; ++k) {
        const float xv = s_xn[xnb + k];
        const float* wr = qkvw + k * 192;          // uniform -> s_load rows
        #pragma unroll
        for (int j = 0; j < DL; ++j) acc[j] = fmaf(xv, wr[j], acc[j]);
    }
    #pragma unroll
    for (int h = 0; h < NH; ++h) {
        #pragma unroll
        for (int i = 0; i < HALFD; ++i) {
            const float a = acc[h*DKH + i], b = acc[h*DKH + HALFD + i];
            q[h*DKH + i]         = a * cs[i] - b * sn[i];
            q[h*DKH + HALFD + i] = a * sn[i] + b * cs[i];
        }
    }

    // ---------------- qkv pass 1: k (rope, -> s_kv cols 0..64) ----------------
    #pragma unroll
    for (int j = 0; j < DL; ++j) acc[j] = 0.f;
    #pragma unroll 2
    for (int k = 0; k < DL; ++k) {
        const float xv = s_xn[xnb + k];
        const float* wr = qkvw + k * 192 + 64;
        #pragma unroll
        for (int j = 0; j < DL; ++j) acc[j] = fmaf(xv, wr[j], acc[j]);
    }
    #pragma unroll
    for (int h = 0; h < NH; ++h) {
        #pragma unroll
        for (int i = 0; i < HALFD; ++i) {
            const float a = acc[h*DKH + i], b = acc[h*DKH + HALFD + i];
            s_kv[kvb + h*DKH + i]         = a * cs[i] - b * sn[i];
            s_kv[kvb + h*DKH + HALFD + i] = a * sn[i] + b * cs[i];
        }
    }

    // ---------------- qkv pass 2: v (-> s_kv cols 64..128) ----------------
    #pragma unroll
    for (int j = 0; j < DL; ++j) acc[j] = 0.f;
    #pragma unroll 2
    for (int k = 0; k < DL; ++k) {
        const float xv = s_xn[xnb + k];
        const float* wr = qkvw + k * 192 + 128;
        #pragma unroll
        for (int j = 0; j < DL; ++j) acc[j] = fmaf(xv, wr[j], acc[j]);
    }
    #pragma unroll
    for (int j = 0; j < DL; ++j) s_kv[kvb + DL + j] = acc[j];

    // q -> s_xn (xn dead; enables rolled-d runtime indexing of q)
    #pragma unroll
    for (int j = 0; j < DL; ++j) s_xn[xnb + j] = q[j];
    __syncthreads();

    // ---------------- attention: scores (rolled d, static sc[] accums) ----------------
    float sc0[LSEQ], sc1[LSEQ];
    #pragma unroll
    for (int tp = 0; tp < LSEQ; ++tp) { sc0[tp] = 0.f; sc1[tp] = 0.f; }
    #pragma unroll 2
    for (int d = 0; d < DKH; ++d) {
        const float q0 = s_xn[xnb + d];
        const float q1 = s_xn[xnb + DKH + d];
        const int r0 = pg * KV_SP + d;
        #pragma unroll
        for (int tp = 0; tp < LSEQ; ++tp) {
            sc0[tp] = fmaf(q0, s_kv[r0 + tp * KV_ST], sc0[tp]);
            sc1[tp] = fmaf(q1, s_kv[r0 + tp * KV_ST + DKH], sc1[tp]);
        }
    }

    // ---------------- causal softmax (fp32) ----------------
    {
        const float inv = 0.17677669529663687f;  // 1/sqrt(32)
        float m0 = -1e30f, m1 = -1e30f;
        #pragma unroll
        for (int tp = 0; tp < LSEQ; ++tp) {
            if (tp <= t) {
                m0 = fmaxf(m0, sc0[tp] * inv);
                m1 = fmaxf(m1, sc1[tp] * inv);
            }
        }
        float p0[LSEQ], p1[LSEQ];
        float s0 = 0.f, s1 = 0.f;
        #pragma unroll
        for (int tp = 0; tp < LSEQ; ++tp) {
            const float e0 = (tp <= t) ? expf(sc0[tp] * inv - m0) : 0.f;
            const float e1 = (tp <= t) ? expf(sc1[tp] * inv - m1) : 0.f;
            p0[tp] = e0; p1[tp] = e1; s0 += e0; s1 += e1;
        }
        const float r0 = 1.f / s0, r1 = 1.f / s1;
        #pragma unroll
        for (int tp = 0; tp < LSEQ; ++tp) {
            s_xn[xnb + tp]        = p0[tp] * r0;   // overwrite q slots (dead)
            s_xn[xnb + LSEQ + tp] = p1[tp] * r1;
        }
    }

    // ---------------- attn @ V (rolled tp, p from LDS) ----------------
    float o[DL];
    #pragma unroll
    for (int j = 0; j < DL; ++j) o[j] = 0.f;
    #pragma unroll 1
    for (int tp = 0; tp < LSEQ; ++tp) {
        const float pv0 = s_xn[xnb + tp];
        const float pv1 = s_xn[xnb + LSEQ + tp];
        const int vr = pg * KV_SP + tp * KV_ST + DL;
        #pragma unroll
        for (int d = 0; d < DKH; ++d) {
            o[d]       = fmaf(pv0, s_kv[vr + d], o[d]);
            o[DKH + d] = fmaf(pv1, s_kv[vr + DKH + d], o[DKH + d]);
        }
    }

    // ---------------- W_o + residual (o staged to s_xn, k-dynamic) ----------------
    #pragma unroll
    for (int j = 0; j < DL; ++j) s_xn[xnb + j] = o[j];
    #pragma unroll 2
    for (int k = 0; k < DL; ++k) {
        const float ov = s_xn[xnb + k];
        const float* wr = wo + k * DL;
        #pragma unroll
        for (int j = 0; j < DL; ++j) x[j] = fmaf(ov, wr[j], x[j]);
    }

    // ---------------- rmsnorm2 -> s_xn ----------------
    {
        float ss = 0.f;
        #pragma unroll
        for (int k = 0; k < DL; ++k) ss = fmaf(x[k], x[k], ss);
        const float rstd = 1.0f / sqrtf(ss * (1.0f / 64.0f) + 1.1920928955078125e-07f);
        #pragma unroll
        for (int k = 0; k < DL; ++k) s_xn[xnb + k] = x[k] * n2w[k] * rstd;
    }

    // ---------------- ffn1 (k-dynamic, 128 reg accums) ----------------
    float hb[DFF];
    #pragma unroll
    for (int j = 0; j < DFF; ++j) hb[j] = 0.f;
    #pragma unroll 2
    for (int k = 0; k < DL; ++k) {
        const float hv = s_xn[xnb + k];
        const float* wr = w1 + k * DFF;
        #pragma unroll
        for (int j = 0; j < DFF; ++j) hb[j] = fmaf(hv, wr[j], hb[j]);
    }
    __syncthreads();   // all attention reads of s_kv complete before overwrite
    #pragma unroll
    for (int j = 0; j < DFF; ++j) {
        const float a = hb[j];
        s_kv[kvb + j] = a / (1.0f + expf(-a));   // silu -> hact
    }

    // ---------------- ffn2 (k-dynamic) + residual ----------------
    float y[DL];
    #pragma unroll
    for (int j = 0; j < DL; ++j) y[j] = 0.f;
    #pragma unroll 2
    for (int k = 0; k < DFF; ++k) {
        const float hv = s_kv[kvb + k];
        const float* wr = w2 + k * DL;
        #pragma unroll
        for (int j = 0; j < DL; ++j) y[j] = fmaf(hv, wr[j], y[j]);
    }
    #pragma unroll
    for (int j = 0; j < DL; ++j) x[j] += y[j];

    // ---------------- rmsnorm3 + masked mean pool ----------------
    {
        float ss = 0.f;
        #pragma unroll
        for (int k = 0; k < DL; ++k) ss = fmaf(x[k], x[k], ss);
        const float rstd = 1.0f / sqrtf(ss * (1.0f / 64.0f) + 1.1920928955078125e-07f);
        const int len = lengths[patch];
        const float msk = (t < len) ? 1.0f : 0.0f;
        const float invlen = 1.0f / (float)len;
        #pragma unroll
        for (int k = 0; k < DL; ++k) {
            float v = x[k] * nw[k] * rstd * msk;
            v += __shfl_xor(v, 1);
            v += __shfl_xor(v, 2);
            v += __shfl_xor(v, 4);
            s_xn[xnb + k] = v * invlen;    // pooled (replicated per token lane's own row)
        }
    }

    // ---------------- proj: each lane does 16 output cols ----------------
    {
        const int c0 = t * 16;
        float ap[16];
        #pragma unroll
        for (int i = 0; i < 16; ++i) ap[i] = pb[c0 + i];
        #pragma unroll 2
        for (int k = 0; k < DL; ++k) {
            const float pk = s_xn[xnb + k];
            const float4* wr = reinterpret_cast<const float4*>(pw + k * DM + c0);
            #pragma unroll
            for (int i = 0; i < 4; ++i) {
                const float4 f = wr[i];
                ap[4*i+0] = fmaf(pk, f.x, ap[4*i+0]);
                ap[4*i+1] = fmaf(pk, f.y, ap[4*i+1]);
                ap[4*i+2] = fmaf(pk, f.z, ap[4*i+2]);
                ap[4*i+3] = fmaf(pk, f.w, ap[4*i+3]);
            }
        }
        float4* op = reinterpret_cast<float4*>(out + (size_t)patch * DM + c0);
        #pragma unroll
        for (int i = 0; i < 4; ++i)
            op[i] = make_float4(ap[4*i+0], ap[4*i+1], ap[4*i+2], ap[4*i+3]);
    }
}

extern "C" void kernel_launch(void* const* d_in, const int* in_sizes, int n_in,
                              void* d_out, int out_size, void* d_ws, size_t ws_size,
                              hipStream_t stream) {
    const int*   tokens  = (const int*)  d_in[0];
    const int*   lengths = (const int*)  d_in[1];
    const float* emb     = (const float*)d_in[2];
    const float* qkvw    = (const float*)d_in[3];
    const float* wo      = (const float*)d_in[4];
    const float* n1w     = (const float*)d_in[5];
    const float* n2w     = (const float*)d_in[6];
    const float* w1      = (const float*)d_in[7];
    const float* w2      = (const float*)d_in[8];
    const float* nw      = (const float*)d_in[9];
    const float* pw      = (const float*)d_in[10];
    const float* pb      = (const float*)d_in[11];
    float* outp = (float*)d_out;

    dim3 grid(N_PATCHES / 8);
    dim3 block(64);
    hipLaunchKernelGGL(enc_kernel, grid, block, 0, stream,
                       tokens, lengths, emb, qkvw, wo, n1w, n2w,
                       w1, w2, nw, pw, pb, outp);
}

// Round 3
// 482.050 us; speedup vs baseline: 6.5659x; 6.5659x over previous
//
#include <hip/hip_runtime.h>
#include <math.h>

#define NP 131072

typedef unsigned short u16;
typedef __bf16 v8bf __attribute__((ext_vector_type(8)));
typedef unsigned short v8u __attribute__((ext_vector_type(8)));
typedef float v4f __attribute__((ext_vector_type(4)));

#define MFMA(a, b, c) __builtin_amdgcn_mfma_f32_16x16x32_bf16(a, b, c, 0, 0, 0)

// RNE float -> bf16 bits
__device__ __forceinline__ u16 f2b(float f) {
    union { float f; unsigned u; } v; v.f = f;
    unsigned r = v.u + 0x7fffu + ((v.u >> 16) & 1u);
    return (u16)(r >> 16);
}
__device__ __forceinline__ v8bf ldfrag(const u16* p) {
    return *(const v8bf*)p;
}
__device__ __forceinline__ v8bf zfrag() {
    v8u z = {0, 0, 0, 0, 0, 0, 0, 0};
    return __builtin_bit_cast(v8bf, z);
}

// ---- weight prep: transpose + bf16 into ws ----
// layout (u16 elems): qkvT[192][64] @0 ; woT[64][64] @12288 ; w1T[128][64] @16384 ;
//                     w2T[64][128] @24576 ; projT[128][64] @32768  (total 40960)
__global__ void prep_weights(const float* __restrict__ qkvw, const float* __restrict__ wo,
                             const float* __restrict__ w1, const float* __restrict__ w2,
                             const float* __restrict__ pw, u16* __restrict__ wt) {
    int i = blockIdx.x * 256 + threadIdx.x;
    if (i < 12288)      { int n = i >> 6, k = i & 63;                wt[i] = f2b(qkvw[k * 192 + n]); }
    else if (i < 16384) { int j = i - 12288; int n = j >> 6, k = j & 63;  wt[i] = f2b(wo[k * 64 + n]); }
    else if (i < 24576) { int j = i - 16384; int n = j >> 6, k = j & 63;  wt[i] = f2b(w1[k * 128 + n]); }
    else if (i < 32768) { int j = i - 24576; int n = j >> 7, k = j & 127; wt[i] = f2b(w2[k * 64 + n]); }
    else if (i < 40960) { int j = i - 32768; int n = j >> 6, k = j & 63;  wt[i] = f2b(pw[k * 128 + n]); }
}

// LDS map (u16 indices). s_a/s_q/s_k: [128 rows][72]; s_vt: [64 d][136 tok-pad]
#define SA_OFF   0              // xn -> P[2][128][32] -> x2n
#define SQ_OFF   (128 * 72)     // Q -> O ; with SK forms h[128][136]
#define SK_OFF   (128 * 72 * 2)
#define SVT_OFF  (128 * 72 * 3) // V^T ; later pooled[16][72]
#define SP_OFF   SA_OFF
#define SH_OFF   SQ_OFF
#define SPOOL_OFF SVT_OFF
#define SMEM_BYTES (128 * 72 * 3 * 2 + 64 * 136 * 2 + 512 + 64)  // 73280

__global__ __launch_bounds__(256, 2)
void enc_mfma(const int* __restrict__ tokens, const int* __restrict__ lengths,
              const float* __restrict__ emb,
              const float* __restrict__ n1w, const float* __restrict__ n2w,
              const float* __restrict__ nw, const float* __restrict__ pb,
              const u16* __restrict__ wt, float* __restrict__ out) {
    __shared__ __align__(16) unsigned char smem[SMEM_BYTES];
    u16* s16 = (u16*)smem;
    int* s_tok = (int*)(smem + 128 * 72 * 3 * 2 + 64 * 136 * 2);
    int* s_len = (int*)(smem + 128 * 72 * 3 * 2 + 64 * 136 * 2 + 512);

    const int tid = threadIdx.x;
    const int l   = tid & 63;
    const int wv  = tid >> 6;
    const int lr  = l & 15;
    const int lk  = l >> 4;
    const int p0  = blockIdx.x << 4;

    // ---------- Ph0: tokens/lengths, embed gather + rmsnorm1 -> s_a (bf16) ----------
    if (tid < 128) s_tok[tid] = tokens[p0 * 8 + tid];
    if (tid < 16)  s_len[tid] = lengths[p0 + tid];
    __syncthreads();
    {
        const int r = tid >> 1, hh = tid & 1;
        const float* er = emb + (size_t)s_tok[r] * 64 + hh * 32;
        float xv[32];
        #pragma unroll
        for (int i = 0; i < 8; ++i) {
            float4 f = ((const float4*)er)[i];
            xv[4*i] = f.x; xv[4*i+1] = f.y; xv[4*i+2] = f.z; xv[4*i+3] = f.w;
        }
        float ss = 0.f;
        #pragma unroll
        for (int k = 0; k < 32; ++k) ss = fmaf(xv[k], xv[k], ss);
        ss += __shfl_xor(ss, 1);
        const float rstd = rsqrtf(ss * 0.015625f + 1.1920928955078125e-07f);
        u16* dst = s16 + SA_OFF + r * 72 + hh * 32;
        #pragma unroll
        for (int k = 0; k < 16; ++k) {
            u16 b0 = f2b(xv[2*k]     * n1w[hh*32 + 2*k]     * rstd);
            u16 b1 = f2b(xv[2*k + 1] * n1w[hh*32 + 2*k + 1] * rstd);
            ((unsigned*)dst)[k] = (unsigned)b0 | ((unsigned)b1 << 16);
        }
    }
    __syncthreads();

    // ---------- Ph1: QKV GEMM (MFMA) + rope -> s_q, s_k, s_vt ----------
    float csr[4], snr[4];
    {
        const float fr = exp2f((float)lr * (-13.287712379549449f / 15.f));
        #pragma unroll
        for (int r = 0; r < 4; ++r) {
            const float th = (float)((lk * 4 + r) & 7) * fr;
            csr[r] = cosf(th); snr[r] = sinf(th);
        }
    }
    {
        v8bf afr[2][2];
        #pragma unroll
        for (int mi = 0; mi < 2; ++mi)
            #pragma unroll
            for (int ks = 0; ks < 2; ++ks)
                afr[mi][ks] = ldfrag(s16 + SA_OFF + (wv*32 + mi*16 + lr) * 72 + ks*32 + lk*8);

        // Q (j=0,1) and K (j=2,3): tile pairs (2j, 2j+1) for rope
        #pragma unroll
        for (int j = 0; j < 4; ++j) {
            v8bf blo[2], bhi[2];
            #pragma unroll
            for (int ks = 0; ks < 2; ++ks) {
                blo[ks] = ldfrag(wt + ((2*j)     * 16 + lr) * 64 + ks*32 + lk*8);
                bhi[ks] = ldfrag(wt + ((2*j + 1) * 16 + lr) * 64 + ks*32 + lk*8);
            }
            const int isq = (j < 2) ? 1 : 0;
            const int head = isq ? j : (j - 2);
            u16* dst = s16 + (isq ? SQ_OFF : SK_OFF);
            #pragma unroll
            for (int mi = 0; mi < 2; ++mi) {
                v4f lo = {0.f, 0.f, 0.f, 0.f}, hi = {0.f, 0.f, 0.f, 0.f};
                #pragma unroll
                for (int ks = 0; ks < 2; ++ks) {
                    lo = MFMA(afr[mi][ks], blo[ks], lo);
                    hi = MFMA(afr[mi][ks], bhi[ks], hi);
                }
                #pragma unroll
                for (int r = 0; r < 4; ++r) {
                    const float c = csr[r], s = snr[r];
                    float nlo = lo[r] * c - hi[r] * s;
                    float nhi = lo[r] * s + hi[r] * c;
                    if (isq) { nlo *= 0.17677669529663687f; nhi *= 0.17677669529663687f; }
                    const int row = wv*32 + mi*16 + lk*4 + r;
                    dst[row * 72 + head*32 + lr]      = f2b(nlo);
                    dst[row * 72 + head*32 + 16 + lr] = f2b(nhi);
                }
            }
        }
        // V tiles (nt 8..11) -> transposed store s_vt[d][tok]
        #pragma unroll
        for (int ntl = 0; ntl < 4; ++ntl) {
            v8bf b[2];
            #pragma unroll
            for (int ks = 0; ks < 2; ++ks)
                b[ks] = ldfrag(wt + ((8 + ntl) * 16 + lr) * 64 + ks*32 + lk*8);
            #pragma unroll
            for (int mi = 0; mi < 2; ++mi) {
                v4f ac = {0.f, 0.f, 0.f, 0.f};
                #pragma unroll
                for (int ks = 0; ks < 2; ++ks) ac = MFMA(afr[mi][ks], b[ks], ac);
                #pragma unroll
                for (int r = 0; r < 4; ++r) {
                    const int row = wv*32 + mi*16 + lk*4 + r;
                    s16[SVT_OFF + (ntl*16 + lr) * 136 + row] = f2b(ac[r]);
                }
            }
        }
    }
    __syncthreads();

    // ---------- Ph2a: block-diag QK^T (MFMA) + causal softmax -> P (s_a region) ----------
    // unit u = head*8 + pair; wave w owns u = 4w..4w+3
    float rsum[4][4];
    #pragma unroll
    for (int uu = 0; uu < 4; ++uu) {
        const int u = wv * 4 + uu;
        const int h = u >> 3, g = u & 7;
        v8bf aq = ldfrag(s16 + SQ_OFF + (g*16 + lr) * 72 + h*32 + lk*8);
        v8bf bk = ldfrag(s16 + SK_OFF + (g*16 + lr) * 72 + h*32 + lk*8);
        v4f zz = {0.f, 0.f, 0.f, 0.f};
        v4f sc = MFMA(aq, bk, zz);
        #pragma unroll
        for (int r = 0; r < 4; ++r) {
            const int row = lk*4 + r;
            const bool valid = ((lr >> 3) == (row >> 3)) && ((lr & 7) <= (row & 7));
            float sv = valid ? sc[r] : -3.0e38f;
            float m = sv;
            m = fmaxf(m, __shfl_xor(m, 1));
            m = fmaxf(m, __shfl_xor(m, 2));
            m = fmaxf(m, __shfl_xor(m, 4));
            m = fmaxf(m, __shfl_xor(m, 8));
            float e = valid ? __expf(sv - m) : 0.f;
            float sum = e;
            sum += __shfl_xor(sum, 1);
            sum += __shfl_xor(sum, 2);
            sum += __shfl_xor(sum, 4);
            sum += __shfl_xor(sum, 8);
            rsum[uu][r] = 1.f / sum;
            s16[SP_OFF + h*4096 + (g*16 + row) * 32 + lr] = f2b(e);
        }
    }
    __syncthreads();

    // ---------- Ph2b: PV (MFMA) -> O (into s_q region, head's 32 cols) ----------
    // K=32 but only 16 real tokens: lanes lk>=2 supply ZERO for BOTH A and B.
    // (Round-2 NaN root cause: B read uninitialized s_vt pad cols for lk>=2;
    //  garbage bf16 NaN * A=0 = NaN. Now 0*0=0, and no uninit/OOB LDS reads.)
    #pragma unroll
    for (int uu = 0; uu < 4; ++uu) {
        const int u = wv * 4 + uu;
        const int h = u >> 3, g = u & 7;
        v8bf ap = zfrag();
        if (lk < 2) ap = ldfrag(s16 + SP_OFF + h*4096 + (g*16 + lr) * 32 + lk*8);
        #pragma unroll
        for (int dl = 0; dl < 2; ++dl) {
            const int dt = h*2 + dl;  // d-tile of this head
            v8bf bv = zfrag();
            if (lk < 2) bv = ldfrag(s16 + SVT_OFF + (dt*16 + lr) * 136 + g*16 + lk*8);
            v4f zz = {0.f, 0.f, 0.f, 0.f};
            v4f oc = MFMA(ap, bv, zz);
            #pragma unroll
            for (int r = 0; r < 4; ++r) {
                const int row = g*16 + lk*4 + r;
                s16[SQ_OFF + row * 72 + dt*16 + lr] = f2b(oc[r] * rsum[uu][r]);
            }
        }
    }
    __syncthreads();

    // ---------- Ph3: Wo GEMM + X residual (emb re-gather as C-in) + norm2 -> x2n (s_a) ----------
    v4f x2[2][4];
    {
        v8bf ao[2][2];
        #pragma unroll
        for (int mi = 0; mi < 2; ++mi)
            #pragma unroll
            for (int ks = 0; ks < 2; ++ks)
                ao[mi][ks] = ldfrag(s16 + SQ_OFF + (wv*32 + mi*16 + lr) * 72 + ks*32 + lk*8);
        #pragma unroll
        for (int mi = 0; mi < 2; ++mi)
            #pragma unroll
            for (int nt = 0; nt < 4; ++nt)
                #pragma unroll
                for (int r = 0; r < 4; ++r)
                    x2[mi][nt][r] = emb[(size_t)s_tok[wv*32 + mi*16 + lk*4 + r] * 64 + nt*16 + lr];
        #pragma unroll
        for (int nt = 0; nt < 4; ++nt) {
            v8bf b[2];
            #pragma unroll
            for (int ks = 0; ks < 2; ++ks)
                b[ks] = ldfrag(wt + 12288 + (nt*16 + lr) * 64 + ks*32 + lk*8);
            #pragma unroll
            for (int mi = 0; mi < 2; ++mi)
                #pragma unroll
                for (int ks = 0; ks < 2; ++ks)
                    x2[mi][nt] = MFMA(ao[mi][ks], b[ks], x2[mi][nt]);
        }
        #pragma unroll
        for (int mi = 0; mi < 2; ++mi) {
            float ssq[4] = {0.f, 0.f, 0.f, 0.f};
            #pragma unroll
            for (int nt = 0; nt < 4; ++nt)
                #pragma unroll
                for (int r = 0; r < 4; ++r) ssq[r] = fmaf(x2[mi][nt][r], x2[mi][nt][r], ssq[r]);
            #pragma unroll
            for (int r = 0; r < 4; ++r) {
                ssq[r] += __shfl_xor(ssq[r], 1);
                ssq[r] += __shfl_xor(ssq[r], 2);
                ssq[r] += __shfl_xor(ssq[r], 4);
                ssq[r] += __shfl_xor(ssq[r], 8);
                ssq[r] = rsqrtf(ssq[r] * 0.015625f + 1.1920928955078125e-07f);
            }
            #pragma unroll
            for (int nt = 0; nt < 4; ++nt) {
                const float nv = n2w[nt*16 + lr];
                #pragma unroll
                for (int r = 0; r < 4; ++r) {
                    const int row = wv*32 + mi*16 + lk*4 + r;
                    s16[SA_OFF + row * 72 + nt*16 + lr] = f2b(x2[mi][nt][r] * nv * ssq[r]);
                }
            }
        }
    }
    __syncthreads();  // protects h-write over O region (cross-wave O reads done)

    // ---------- Ph4: FFN1 (MFMA) + silu -> s_h (spans s_q+s_k) ----------
    {
        v8bf a[2][2];
        #pragma unroll
        for (int mi = 0; mi < 2; ++mi)
            #pragma unroll
            for (int ks = 0; ks < 2; ++ks)
                a[mi][ks] = ldfrag(s16 + SA_OFF + (wv*32 + mi*16 + lr) * 72 + ks*32 + lk*8);
        #pragma unroll
        for (int nt = 0; nt < 8; ++nt) {
            v8bf b[2];
            #pragma unroll
            for (int ks = 0; ks < 2; ++ks)
                b[ks] = ldfrag(wt + 16384 + (nt*16 + lr) * 64 + ks*32 + lk*8);
            #pragma unroll
            for (int mi = 0; mi < 2; ++mi) {
                v4f hc = {0.f, 0.f, 0.f, 0.f};
                #pragma unroll
                for (int ks = 0; ks < 2; ++ks) hc = MFMA(a[mi][ks], b[ks], hc);
                #pragma unroll
                for (int r = 0; r < 4; ++r) {
                    const float v = hc[r];
                    const float sl = v / (1.f + __expf(-v));
                    const int row = wv*32 + mi*16 + lk*4 + r;
                    s16[SH_OFF + row * 136 + nt*16 + lr] = f2b(sl);
                }
            }
        }
    }
    // own-row produce/consume: no barrier needed before Ph5

    // ---------- Ph5: FFN2 (MFMA, C-in = x2) + norm3 + masked mean pool -> s_pool ----------
    {
        v8bf a2[2][4];
        #pragma unroll
        for (int mi = 0; mi < 2; ++mi)
            #pragma unroll
            for (int ks = 0; ks < 4; ++ks)
                a2[mi][ks] = ldfrag(s16 + SH_OFF + (wv*32 + mi*16 + lr) * 136 + ks*32 + lk*8);
        #pragma unroll
        for (int nt = 0; nt < 4; ++nt) {
            v8bf b[4];
            #pragma unroll
            for (int ks = 0; ks < 4; ++ks)
                b[ks] = ldfrag(wt + 24576 + (nt*16 + lr) * 128 + ks*32 + lk*8);
            #pragma unroll
            for (int mi = 0; mi < 2; ++mi)
                #pragma unroll
                for (int ks = 0; ks < 4; ++ks)
                    x2[mi][nt] = MFMA(a2[mi][ks], b[ks], x2[mi][nt]);
        }
        #pragma unroll
        for (int mi = 0; mi < 2; ++mi) {
            float ssq[4] = {0.f, 0.f, 0.f, 0.f};
            #pragma unroll
            for (int nt = 0; nt < 4; ++nt)
                #pragma unroll
                for (int r = 0; r < 4; ++r) ssq[r] = fmaf(x2[mi][nt][r], x2[mi][nt][r], ssq[r]);
            #pragma unroll
            for (int r = 0; r < 4; ++r) {
                ssq[r] += __shfl_xor(ssq[r], 1);
                ssq[r] += __shfl_xor(ssq[r], 2);
                ssq[r] += __shfl_xor(ssq[r], 4);
                ssq[r] += __shfl_xor(ssq[r], 8);
                ssq[r] = rsqrtf(ssq[r] * 0.015625f + 1.1920928955078125e-07f);
            }
            const int lp = wv*4 + mi*2 + (lk >> 1);
            const int len = s_len[lp];
            const float invl = 1.f / (float)len;
            #pragma unroll
            for (int nt = 0; nt < 4; ++nt) {
                const float nv = nw[nt*16 + lr];
                float part = 0.f;
                #pragma unroll
                for (int r = 0; r < 4; ++r) {
                    const int tt = (lk & 1) * 4 + r;
                    const float xn3 = x2[mi][nt][r] * nv * ssq[r];
                    part += (tt < len) ? xn3 : 0.f;
                }
                part += __shfl_xor(part, 16);
                if ((lk & 1) == 0)
                    s16[SPOOL_OFF + lp * 72 + nt*16 + lr] = f2b(part * invl);
            }
        }
    }
    __syncthreads();

    // ---------- Ph6: proj [16x64]@[64x128] + bias -> out ----------
    {
        v8bf ap2[2];
        #pragma unroll
        for (int ks = 0; ks < 2; ++ks)
            ap2[ks] = ldfrag(s16 + SPOOL_OFF + lr * 72 + ks*32 + lk*8);
        #pragma unroll
        for (int ntl = 0; ntl < 2; ++ntl) {
            const int nt = wv * 2 + ntl;
            v8bf b[2];
            #pragma unroll
            for (int ks = 0; ks < 2; ++ks)
                b[ks] = ldfrag(wt + 32768 + (nt*16 + lr) * 64 + ks*32 + lk*8);
            const float bias = pb[nt*16 + lr];
            v4f ac = {bias, bias, bias, bias};
            #pragma unroll
            for (int ks = 0; ks < 2; ++ks) ac = MFMA(ap2[ks], b[ks], ac);
            #pragma unroll
            for (int r = 0; r < 4; ++r)
                out[(size_t)(p0 + lk*4 + r) * 128 + nt*16 + lr] = ac[r];
        }
    }
}

extern "C" void kernel_launch(void* const* d_in, const int* in_sizes, int n_in,
                              void* d_out, int out_size, void* d_ws, size_t ws_size,
                              hipStream_t stream) {
    const int*   tokens  = (const int*)  d_in[0];
    const int*   lengths = (const int*)  d_in[1];
    const float* emb     = (const float*)d_in[2];
    const float* qkvw    = (const float*)d_in[3];
    const float* wo      = (const float*)d_in[4];
    const float* n1w     = (const float*)d_in[5];
    const float* n2w     = (const float*)d_in[6];
    const float* w1      = (const float*)d_in[7];
    const float* w2      = (const float*)d_in[8];
    const float* nw      = (const float*)d_in[9];
    const float* pw      = (const float*)d_in[10];
    const float* pb      = (const float*)d_in[11];
    float* outp = (float*)d_out;
    u16* wt = (u16*)d_ws;

    hipLaunchKernelGGL(prep_weights, dim3(160), dim3(256), 0, stream,
                       qkvw, wo, w1, w2, pw, wt);
    hipLaunchKernelGGL(enc_mfma, dim3(NP / 16), dim3(256), 0, stream,
                       tokens, lengths, emb, n1w, n2w, nw, pb, (const u16*)wt, outp);
}

// Round 5
// 403.855 us; speedup vs baseline: 7.8372x; 1.1936x over previous
//
#include <hip/hip_runtime.h>
#include <math.h>

#define NP 131072

typedef unsigned short u16;
typedef __bf16 v8bf __attribute__((ext_vector_type(8)));
typedef unsigned short v8u __attribute__((ext_vector_type(8)));
typedef float v4f __attribute__((ext_vector_type(4)));

#define MFMA(a, b, c) __builtin_amdgcn_mfma_f32_16x16x32_bf16(a, b, c, 0, 0, 0)
#define EPS 1.1920928955078125e-07f

__device__ __forceinline__ u16 f2b(float f) { return __builtin_bit_cast(u16, (__bf16)f); }
__device__ __forceinline__ unsigned f2b2(float a, float b) {
    return (unsigned)f2b(a) | ((unsigned)f2b(b) << 16);
}
__device__ __forceinline__ float frcp(float x) { return __builtin_amdgcn_rcpf(x); }
__device__ __forceinline__ float frsq(float x) { return __builtin_amdgcn_rsqf(x); }
__device__ __forceinline__ v8bf ldfrag(const u16* p) { return *(const v8bf*)p; }
__device__ __forceinline__ v8bf zfrag() { v8u z = {0,0,0,0,0,0,0,0}; return __builtin_bit_cast(v8bf, z); }

// ---- weight prep: transpose + bf16 into ws ----
// layout (u16): qkvT[192][64] @0 ; woT[64][64] @12288 ; w1T[128][64] @16384 ;
//               w2T[64][128] @24576 ; projT[128][64] @32768
__global__ void prep_weights(const float* __restrict__ qkvw, const float* __restrict__ wo,
                             const float* __restrict__ w1, const float* __restrict__ w2,
                             const float* __restrict__ pw, u16* __restrict__ wt) {
    int i = blockIdx.x * 256 + threadIdx.x;
    if (i < 12288)      { int n = i >> 6, k = i & 63;                wt[i] = f2b(qkvw[k * 192 + n]); }
    else if (i < 16384) { int j = i - 12288; int n = j >> 6, k = j & 63;  wt[i] = f2b(wo[k * 64 + n]); }
    else if (i < 24576) { int j = i - 16384; int n = j >> 6, k = j & 63;  wt[i] = f2b(w1[k * 128 + n]); }
    else if (i < 32768) { int j = i - 24576; int n = j >> 7, k = j & 127; wt[i] = f2b(w2[k * 64 + n]); }
    else if (i < 40960) { int j = i - 32768; int n = j >> 6, k = j & 63;  wt[i] = f2b(pw[k * 128 + n]); }
}

// LDS (u16 idx):
//  R0 8192: xn [128][64] swizzled -> V^T [64][128] swizzled (R4 BUG: was [*][64], rows
//           collided for token chunks 8..15 -> cross-wave clobber; now full [64][128])
//           -> pooled [16][64] swizzled
//  R1 9216: Q [128][72] -> P per-wave pack (wv*2304, [4 units][16][32]) -> x2n -> h-low
//  R2 9216: K [128][72] -> O -> h-high.   h: [128][136] @ SHA=R1A.
// Total 26624 u16 = 53248 B -> 3 blocks/CU.
#define R0A 0
#define R1A 8192
#define R2A 17408
#define SHA 8192
#define SMEM_U16 26624

__global__ __launch_bounds__(256, 3)
void enc_mfma(const int* __restrict__ tokens, const int* __restrict__ lengths,
              const float* __restrict__ emb,
              const float* __restrict__ n1w, const float* __restrict__ n2w,
              const float* __restrict__ nw, const float* __restrict__ pb,
              const u16* __restrict__ wt, float* __restrict__ out) {
    __shared__ __align__(16) u16 s16[SMEM_U16];

    const int tid = threadIdx.x;
    const int l   = tid & 63;
    const int wv  = tid >> 6;
    const int lr  = l & 15;
    const int lk  = l >> 4;
    const int p0  = blockIdx.x << 4;

    // ---------- Ph0: embed gather + rmsnorm1 -> R0 (swizzled bf16) ----------
    {
        const int r = tid >> 1, hh = tid & 1;
        const int tok = tokens[p0 * 8 + r];
        const float* er = emb + (size_t)tok * 64 + hh * 32;
        float xv[32];
        #pragma unroll
        for (int i = 0; i < 8; ++i) {
            float4 f = ((const float4*)er)[i];
            xv[4*i] = f.x; xv[4*i+1] = f.y; xv[4*i+2] = f.z; xv[4*i+3] = f.w;
        }
        float ss = 0.f;
        #pragma unroll
        for (int k = 0; k < 32; ++k) ss = fmaf(xv[k], xv[k], ss);
        ss += __shfl_xor(ss, 1);
        const float rstd = frsq(ss * 0.015625f + EPS);
        const int key = r & 7;
        #pragma unroll
        for (int k = 0; k < 16; ++k) {
            const float a = xv[2*k]     * n1w[hh*32 + 2*k]     * rstd;
            const float b = xv[2*k + 1] * n1w[hh*32 + 2*k + 1] * rstd;
            const int addr = r * 64 + (((hh*4 + (k >> 2)) ^ key) << 3) + ((2*k) & 7);
            *(unsigned*)(s16 + addr) = f2b2(a, b);
        }
    }

    // rope tables for rows lk*4+r (token t = row&7)
    float csr[4], snr[4];
    {
        const float fr = exp2f((float)lr * (-13.287712379549449f / 15.f));
        #pragma unroll
        for (int r = 0; r < 4; ++r) {
            const float th = (float)((lk*4 + r) & 7) * fr;
            csr[r] = __cosf(th); snr[r] = __sinf(th);
        }
    }

    // ---------- Ph1: QKV GEMM + rope -> Q(R1), K(R2), V^T(R0 swizzled) ----------
    {
        v8bf afr[2][2];
        #pragma unroll
        for (int mi = 0; mi < 2; ++mi)
            #pragma unroll
            for (int ks = 0; ks < 2; ++ks)
                afr[mi][ks] = ldfrag(s16 + R0A + (wv*32 + mi*16 + lr) * 64
                                     + (((ks*4 + lk) ^ (lr & 7)) << 3));
        __syncthreads();   // BARRIER A: all xn reads done before V^T overwrites R0

        #pragma unroll
        for (int j = 0; j < 4; ++j) {        // Q (j=0,1), K (j=2,3)
            v8bf blo[2], bhi[2];
            #pragma unroll
            for (int ks = 0; ks < 2; ++ks) {
                blo[ks] = ldfrag(wt + ((2*j)     * 16 + lr) * 64 + ks*32 + lk*8);
                bhi[ks] = ldfrag(wt + ((2*j + 1) * 16 + lr) * 64 + ks*32 + lk*8);
            }
            const int isq = (j < 2) ? 1 : 0;
            const int head = isq ? j : (j - 2);
            const int dst = isq ? R1A : R2A;
            #pragma unroll
            for (int mi = 0; mi < 2; ++mi) {
                v4f lo = {0.f,0.f,0.f,0.f}, hi = {0.f,0.f,0.f,0.f};
                #pragma unroll
                for (int ks = 0; ks < 2; ++ks) {
                    lo = MFMA(afr[mi][ks], blo[ks], lo);
                    hi = MFMA(afr[mi][ks], bhi[ks], hi);
                }
                #pragma unroll
                for (int r = 0; r < 4; ++r) {
                    const float c = csr[r], s = snr[r];
                    float nlo = lo[r] * c - hi[r] * s;
                    float nhi = lo[r] * s + hi[r] * c;
                    if (isq) { nlo *= 0.17677669529663687f; nhi *= 0.17677669529663687f; }
                    const int row = wv*32 + mi*16 + lk*4 + r;
                    s16[dst + row*72 + head*32 + lr]      = f2b(nlo);
                    s16[dst + row*72 + head*32 + 16 + lr] = f2b(nhi);
                }
            }
        }
        // V -> R0 as V^T[d][tok], full [64][128], per-row 16-chunk XOR swizzle (key = d&15)
        #pragma unroll
        for (int ntl = 0; ntl < 4; ++ntl) {
            v8bf b[2];
            #pragma unroll
            for (int ks = 0; ks < 2; ++ks)
                b[ks] = ldfrag(wt + ((8 + ntl) * 16 + lr) * 64 + ks*32 + lk*8);
            #pragma unroll
            for (int mi = 0; mi < 2; ++mi) {
                v4f ac = {0.f,0.f,0.f,0.f};
                #pragma unroll
                for (int ks = 0; ks < 2; ++ks) ac = MFMA(afr[mi][ks], b[ks], ac);
                #pragma unroll
                for (int r = 0; r < 4; ++r) {
                    const int d = ntl*16 + lr;
                    const int tok = wv*32 + mi*16 + lk*4 + r;
                    s16[R0A + d*128 + (((tok >> 3) ^ (d & 15)) << 3) + (tok & 7)] = f2b(ac[r]);
                }
            }
        }
    }
    // Q,K,V^T,P,O all own-wave produced/consumed -> no barrier through attention

    // ---------- Ph2a: QK^T + causal softmax (no max-sub) -> P (R1, per-wave pack) ----------
    // unit uu: h = uu>>1, g = 2*wv + (uu&1)  (own 32-row band)
    const int pbase = R1A + wv * 2304;
    float rsum[4][4];
    {
        v8bf aq[4], bk[4];
        #pragma unroll
        for (int uu = 0; uu < 4; ++uu) {
            const int h = uu >> 1, g = 2*wv + (uu & 1);
            aq[uu] = ldfrag(s16 + R1A + (g*16 + lr)*72 + h*32 + lk*8);
            bk[uu] = ldfrag(s16 + R2A + (g*16 + lr)*72 + h*32 + lk*8);
        }
        #pragma unroll
        for (int uu = 0; uu < 4; ++uu) {
            v4f zz = {0.f,0.f,0.f,0.f};
            v4f sc = MFMA(aq[uu], bk[uu], zz);
            #pragma unroll
            for (int r = 0; r < 4; ++r) {
                const int row = lk*4 + r;
                const bool valid = ((lr >> 3) == (row >> 3)) && ((lr & 7) <= (row & 7));
                float e = valid ? __expf(sc[r]) : 0.f;
                float sum = e;
                sum += __shfl_xor(sum, 1);
                sum += __shfl_xor(sum, 2);
                sum += __shfl_xor(sum, 4);
                sum += __shfl_xor(sum, 8);
                rsum[uu][r] = frcp(sum);
                s16[pbase + uu*512 + row*32 + lr] = f2b(e);
            }
        }
    }

    // ---------- Ph2b: PV -> O (R2, own band) ----------
    #pragma unroll
    for (int uu = 0; uu < 4; ++uu) {
        const int h = uu >> 1, g = 2*wv + (uu & 1);
        v8bf ap = zfrag();
        if (lk < 2) ap = ldfrag(s16 + pbase + uu*512 + lr*32 + lk*8);
        #pragma unroll
        for (int dl = 0; dl < 2; ++dl) {
            const int dt = h*2 + dl;
            v8bf bv = zfrag();
            if (lk < 2) bv = ldfrag(s16 + R0A + (dt*16 + lr)*128
                                    + (((2*g + lk) ^ lr) << 3));
            v4f zz = {0.f,0.f,0.f,0.f};
            v4f oc = MFMA(ap, bv, zz);
            #pragma unroll
            for (int r = 0; r < 4; ++r) {
                const int row = g*16 + lk*4 + r;
                s16[R2A + row*72 + dt*16 + lr] = f2b(oc[r] * rsum[uu][r]);
            }
        }
    }

    // ---------- Ph3: Wo GEMM + residual (emb re-gather) + norm2 -> x2n (R1 own band) ----------
    v4f x2[2][4];
    {
        v8bf ao[2][2];
        #pragma unroll
        for (int mi = 0; mi < 2; ++mi)
            #pragma unroll
            for (int ks = 0; ks < 2; ++ks)
                ao[mi][ks] = ldfrag(s16 + R2A + (wv*32 + mi*16 + lr)*72 + ks*32 + lk*8);
        int trow[2][4];
        #pragma unroll
        for (int mi = 0; mi < 2; ++mi)
            #pragma unroll
            for (int r = 0; r < 4; ++r)
                trow[mi][r] = tokens[p0*8 + wv*32 + mi*16 + lk*4 + r];
        #pragma unroll
        for (int mi = 0; mi < 2; ++mi)
            #pragma unroll
            for (int nt = 0; nt < 4; ++nt)
                #pragma unroll
                for (int r = 0; r < 4; ++r)
                    x2[mi][nt][r] = emb[(size_t)trow[mi][r] * 64 + nt*16 + lr];
        #pragma unroll
        for (int nt = 0; nt < 4; ++nt) {
            v8bf b[2];
            #pragma unroll
            for (int ks = 0; ks < 2; ++ks)
                b[ks] = ldfrag(wt + 12288 + (nt*16 + lr)*64 + ks*32 + lk*8);
            #pragma unroll
            for (int mi = 0; mi < 2; ++mi)
                #pragma unroll
                for (int ks = 0; ks < 2; ++ks)
                    x2[mi][nt] = MFMA(ao[mi][ks], b[ks], x2[mi][nt]);
        }
        #pragma unroll
        for (int mi = 0; mi < 2; ++mi) {
            float ssq[4] = {0.f,0.f,0.f,0.f};
            #pragma unroll
            for (int nt = 0; nt < 4; ++nt)
                #pragma unroll
                for (int r = 0; r < 4; ++r) ssq[r] = fmaf(x2[mi][nt][r], x2[mi][nt][r], ssq[r]);
            #pragma unroll
            for (int r = 0; r < 4; ++r) {
                ssq[r] += __shfl_xor(ssq[r], 1);
                ssq[r] += __shfl_xor(ssq[r], 2);
                ssq[r] += __shfl_xor(ssq[r], 4);
                ssq[r] += __shfl_xor(ssq[r], 8);
                ssq[r] = frsq(ssq[r] * 0.015625f + EPS);
            }
            #pragma unroll
            for (int nt = 0; nt < 4; ++nt) {
                const float nv = n2w[nt*16 + lr];
                #pragma unroll
                for (int r = 0; r < 4; ++r) {
                    const int row = wv*32 + mi*16 + lk*4 + r;
                    s16[R1A + row*72 + nt*16 + lr] = f2b(x2[mi][nt][r] * nv * ssq[r]);
                }
            }
        }
    }

    // ---------- Ph4: FFN1 + silu -> h [128][136] spanning R1+R2 ----------
    {
        v8bf a[2][2];
        #pragma unroll
        for (int mi = 0; mi < 2; ++mi)
            #pragma unroll
            for (int ks = 0; ks < 2; ++ks)
                a[mi][ks] = ldfrag(s16 + R1A + (wv*32 + mi*16 + lr)*72 + ks*32 + lk*8);
        __syncthreads();   // BARRIER B: all P/O/x2n/V^T reads done before h overwrites R1+R2
        #pragma unroll
        for (int nt = 0; nt < 8; ++nt) {
            v8bf b[2];
            #pragma unroll
            for (int ks = 0; ks < 2; ++ks)
                b[ks] = ldfrag(wt + 16384 + (nt*16 + lr)*64 + ks*32 + lk*8);
            #pragma unroll
            for (int mi = 0; mi < 2; ++mi) {
                v4f hc = {0.f,0.f,0.f,0.f};
                #pragma unroll
                for (int ks = 0; ks < 2; ++ks) hc = MFMA(a[mi][ks], b[ks], hc);
                #pragma unroll
                for (int r = 0; r < 4; ++r) {
                    const float v = hc[r];
                    const float sl = v * frcp(1.f + __expf(-v));
                    const int row = wv*32 + mi*16 + lk*4 + r;
                    s16[SHA + row*136 + nt*16 + lr] = f2b(sl);
                }
            }
        }
    }

    // ---------- Ph5: FFN2 (C-in = x2) + norm3 + masked mean pool -> pooled (R0) ----------
    {
        v8bf a2[2][4];
        #pragma unroll
        for (int mi = 0; mi < 2; ++mi)
            #pragma unroll
            for (int ks = 0; ks < 4; ++ks)
                a2[mi][ks] = ldfrag(s16 + SHA + (wv*32 + mi*16 + lr)*136 + ks*32 + lk*8);
        #pragma unroll
        for (int nt = 0; nt < 4; ++nt) {
            v8bf b[4];
            #pragma unroll
            for (int ks = 0; ks < 4; ++ks)
                b[ks] = ldfrag(wt + 24576 + (nt*16 + lr)*128 + ks*32 + lk*8);
            #pragma unroll
            for (int mi = 0; mi < 2; ++mi)
                #pragma unroll
                for (int ks = 0; ks < 4; ++ks)
                    x2[mi][nt] = MFMA(a2[mi][ks], b[ks], x2[mi][nt]);
        }
        #pragma unroll
        for (int mi = 0; mi < 2; ++mi) {
            float ssq[4] = {0.f,0.f,0.f,0.f};
            #pragma unroll
            for (int nt = 0; nt < 4; ++nt)
                #pragma unroll
                for (int r = 0; r < 4; ++r) ssq[r] = fmaf(x2[mi][nt][r], x2[mi][nt][r], ssq[r]);
            #pragma unroll
            for (int r = 0; r < 4; ++r) {
                ssq[r] += __shfl_xor(ssq[r], 1);
                ssq[r] += __shfl_xor(ssq[r], 2);
                ssq[r] += __shfl_xor(ssq[r], 4);
                ssq[r] += __shfl_xor(ssq[r], 8);
                ssq[r] = frsq(ssq[r] * 0.015625f + EPS);
            }
            const int lp = wv*4 + mi*2 + (lk >> 1);
            const int len = lengths[p0 + lp];
            const float invl = frcp((float)len);
            #pragma unroll
            for (int nt = 0; nt < 4; ++nt) {
                const float nv = nw[nt*16 + lr];
                float part = 0.f;
                #pragma unroll
                for (int r = 0; r < 4; ++r) {
                    const int tt = (lk & 1) * 4 + r;
                    const float xn3 = x2[mi][nt][r] * nv * ssq[r];
                    part += (tt < len) ? xn3 : 0.f;
                }
                part += __shfl_xor(part, 16);
                if ((lk & 1) == 0) {
                    const int addr = R0A + lp*64
                        + (((2*nt + (lr >> 3)) ^ (lp & 7)) << 3) + (lr & 7);
                    s16[addr] = f2b(part * invl);
                }
            }
        }
    }
    __syncthreads();   // BARRIER C: pooled visible to all waves

    // ---------- Ph6: proj [16x64]@[64x128] + bias -> out ----------
    {
        v8bf ap2[2];
        #pragma unroll
        for (int ks = 0; ks < 2; ++ks)
            ap2[ks] = ldfrag(s16 + R0A + lr*64 + (((ks*4 + lk) ^ (lr & 7)) << 3));
        #pragma unroll
        for (int ntl = 0; ntl < 2; ++ntl) {
            const int nt = wv*2 + ntl;
            v8bf b[2];
            #pragma unroll
            for (int ks = 0; ks < 2; ++ks)
                b[ks] = ldfrag(wt + 32768 + (nt*16 + lr)*64 + ks*32 + lk*8);
            const float bias = pb[nt*16 + lr];
            v4f ac = {bias, bias, bias, bias};
            #pragma unroll
            for (int ks = 0; ks < 2; ++ks) ac = MFMA(ap2[ks], b[ks], ac);
            #pragma unroll
            for (int r = 0; r < 4; ++r)
                out[(size_t)(p0 + lk*4 + r) * 128 + nt*16 + lr] = ac[r];
        }
    }
}

extern "C" void kernel_launch(void* const* d_in, const int* in_sizes, int n_in,
                              void* d_out, int out_size, void* d_ws, size_t ws_size,
                              hipStream_t stream) {
    const int*   tokens  = (const int*)  d_in[0];
    const int*   lengths = (const int*)  d_in[1];
    const float* emb     = (const float*)d_in[2];
    const float* qkvw    = (const float*)d_in[3];
    const float* wo      = (const float*)d_in[4];
    const float* n1w     = (const float*)d_in[5];
    const float* n2w     = (const float*)d_in[6];
    const float* w1      = (const float*)d_in[7];
    const float* w2      = (const float*)d_in[8];
    const float* nw      = (const float*)d_in[9];
    const float* pw      = (const float*)d_in[10];
    const float* pb      = (const float*)d_in[11];
    float* outp = (float*)d_out;
    u16* wt = (u16*)d_ws;

    hipLaunchKernelGGL(prep_weights, dim3(160), dim3(256), 0, stream,
                       qkvw, wo, w1, w2, pw, wt);
    hipLaunchKernelGGL(enc_mfma, dim3(NP / 16), dim3(256), 0, stream,
                       tokens, lengths, emb, n1w, n2w, nw, pb, (const u16*)wt, outp);
}